// Round 9
// baseline (390.156 us; speedup 1.0000x reference)
//
#include <hip/hip_runtime.h>

#define NPTS 8192
#define NCH 8
#define STRIDE 6144
#define TOTAL 51200
#define FADE 1228
#define SROWS 16     // smoother rows per block (512 blocks = 2/CU)
#define QW 16        // queries (waves) per k_nn block

typedef unsigned long long u64;

// ---------------------------------------------------------------------------
// copy ALL chunks -> fin, init jmax to -1, build C4 = (x,y,z,x^2+y^2+z^2) for
// chunks 1..7, pre-transpose W2.
// ROUND-9 FIX: fp contract(off) -- without it, cc compiled as an fma chain,
// changing d bits vs the verified argmin and flipping near-tie winners
// (the identical 1.306e-2 absmax across rounds 7 AND 8 localized the bug here:
// both rounds shared only this kernel's new FP math).
__global__ void k_setup(const float* __restrict__ chunks, float* __restrict__ fin,
                        int* __restrict__ jmax_all, float4* __restrict__ C4,
                        const float* __restrict__ w2g, float* __restrict__ W2T) {
#pragma clang fp contract(off)
    int i = blockIdx.x * 256 + threadIdx.x;            // grid covers 196608
    if (i < NCH * NPTS * 3) fin[i] = chunks[i];
    if (i < (NCH - 1) * NPTS) {
        jmax_all[i] = -1;
        int c = 1 + (i >> 13);          // chunk 1..7
        int t = i & (NPTS - 1);
        const float* s = chunks + ((size_t)c * NPTS + t) * 3;
        float x = s[0], y = s[1], z = s[2];
        float cc = (x * x + y * y) + z * z;
        C4[i] = make_float4(x, y, z, cc);
    }
    if (i < 5120) {
        int co = i / 160;
        int r = i - co * 160;
        int ci = r / 5;
        int k = r - ci * 5;
        W2T[(ci * 5 + k) * 32 + co] = w2g[i];
    }
}

// ---------------------------------------------------------------------------
// FUSED argmin + resolve. 512 blocks x 1024 threads; wave w owns query
// j = blockIdx.x*16 + w. All 8192 candidates scanned in 8 LDS-staged
// segments of 1024 (register-prefetched, barrier-protected). Per-lane scan
// covers k = lane+64u ascending, strict < (lowest k on ties); d chain
// bit-identical: g = fma(p2,cz, fma(p1,cy, p0*cx)); d = fma(-2,g, pp+cc).
// Winner via 6-step butterfly on explicit 32-bit halves, lexicographic
// (mapped_d, k) min == the verified team/atomicMin semantics.
// Resolve MLP: fully convergent, shuffle-only cross-lane; channel chains
// are verbatim ci-ascending from the verified k_resolve.
__global__ __launch_bounds__(1024, 8) void k_nn(
        const float* __restrict__ P, const float4* __restrict__ C4,
        const float* __restrict__ wp_w1, const float* __restrict__ wp_b1,
        const float* __restrict__ wp_w2, const float* __restrict__ wp_b2,
        const float* __restrict__ wp_w3, const float* __restrict__ wp_b3,
        float* __restrict__ fused, int* __restrict__ mi, int* __restrict__ jmax) {
#pragma clang fp contract(off)
    __shared__ float4 sc[1024];        // candidate segment
    __shared__ float Wp[780];          // w1[0:192) b1[192:224) w2[224:736) b2[736:752) w3[752:768) b3[768]
    __shared__ float Wt2[512];         // wp_w2 transposed: [ci*16+o]
    int tid = threadIdx.x;
    int w = tid >> 6;                  // wave id == local query index
    int lane = tid & 63;
    int j = blockIdx.x * QW + w;

    // ---- stage MLP weights (once; read-only after the first barrier) ----
    if (tid < 780) {
        int i = tid;
        float v;
        if (i < 192) v = wp_w1[i];
        else if (i < 224) v = wp_b1[i - 192];
        else if (i < 736) v = wp_w2[i - 224];
        else if (i < 752) v = wp_b2[i - 736];
        else if (i < 768) v = wp_w3[i - 752];
        else v = wp_b3[0];
        Wp[i] = v;
    }
    if (tid < 512) {
        int o = tid >> 5, ci = tid & 31;
        Wt2[ci * 16 + o] = wp_w2[tid];
    }

    // ---- query point (wave-uniform broadcast load) ----
    float p0 = P[j * 3 + 0], p1 = P[j * 3 + 1], p2 = P[j * 3 + 2];
    float pp = (p0 * p0 + p1 * p1) + p2 * p2;
    float best = 3.4e38f;
    int bk = lane;

    // ---- scan all 8192 candidates in 8 barrier-protected segments ----
    float4 pf = C4[tid];
    for (int s = 0; s < 8; ++s) {
        __syncthreads();               // readers of previous segment done (fences Wp/Wt2 at s=0)
        sc[tid] = pf;
        if (s < 7) pf = C4[(s + 1) * 1024 + tid];
        __syncthreads();               // segment ready
        int kbase = s * 1024;
#pragma unroll
        for (int u = 0; u < 16; ++u) {
            float4 f = sc[lane + 64 * u];
            float g = __builtin_fmaf(p2, f.z, __builtin_fmaf(p1, f.y, p0 * f.x));
            float sadd = pp + f.w;
            float d = __builtin_fmaf(-2.0f, g, sadd);
            int k = kbase + lane + 64 * u;
            if (d < best) { best = d; bk = k; }   // strict <: lowest k wins ties
        }
    }

    // ---- pack + 64-lane butterfly on explicit 32-bit halves ----
    unsigned ud = __float_as_uint(best);
    if (ud == 0x80000000u) ud = 0u;                 // canonicalize -0 -> +0 (bitwise)
    ud = (ud & 0x80000000u) ? ~ud : (ud | 0x80000000u);   // order-preserving map
    unsigned hi = ud;
    unsigned lo = (unsigned)bk;
#pragma unroll
    for (int s = 1; s < 64; s <<= 1) {
        unsigned ohi = (unsigned)__shfl_xor((int)hi, s);
        unsigned olo = (unsigned)__shfl_xor((int)lo, s);
        if (ohi < hi || (ohi == hi && olo < lo)) { hi = ohi; lo = olo; }
    }
    int m = (int)lo;

    // ---- resolve MLP: convergent, shuffle-only (bit-identical chains) ----
    float4 cm = C4[m];                 // .xyz are exact copies of C[m]; m wave-uniform
    int c1 = lane & 31;                // h1 channel (lanes 32-63 duplicate: harmless)
    float acc1 = 0.0f;
    acc1 = __builtin_fmaf(p0,   Wp[c1 * 6 + 0], acc1);
    acc1 = __builtin_fmaf(p1,   Wp[c1 * 6 + 1], acc1);
    acc1 = __builtin_fmaf(p2,   Wp[c1 * 6 + 2], acc1);
    acc1 = __builtin_fmaf(cm.x, Wp[c1 * 6 + 3], acc1);
    acc1 = __builtin_fmaf(cm.y, Wp[c1 * 6 + 4], acc1);
    acc1 = __builtin_fmaf(cm.z, Wp[c1 * 6 + 5], acc1);
    float h1 = fmaxf(acc1 + Wp[192 + c1], 0.0f);

    int c2 = lane & 15;                // h2 channel (4x duplicated)
    float acc2 = 0.0f;
#pragma unroll
    for (int ci = 0; ci < 32; ++ci)
        acc2 = __builtin_fmaf(__shfl(h1, ci), Wt2[ci * 16 + c2], acc2);
    float h2 = fmaxf(acc2 + Wp[736 + c2], 0.0f);

    float acc3 = 0.0f;                 // z on all lanes (identical value)
#pragma unroll
    for (int ci = 0; ci < 16; ++ci)
        acc3 = __builtin_fmaf(__shfl(h2, ci), Wp[752 + ci], acc3);
    float z = acc3 + Wp[768];
    float ww = 1.0f / (1.0f + expf(-z));
    float omw = 1.0f - ww;

    if (lane < 3) {
        float xe = (lane == 0) ? p0 : (lane == 1) ? p1 : p2;
        float ce = (lane == 0) ? cm.x : (lane == 1) ? cm.y : cm.z;
        float t1 = ww * xe;
        float t2 = omw * ce;
        fused[lane * NPTS + j] = t1 + t2;
    }
    if (lane == 0) {
        mi[j] = m;
        atomicMax(&jmax[m], j);
    }
}

// ---------------------------------------------------------------------------
// fused boundary smoother + scatter epilogue (verified round-6 body).
__global__ __launch_bounds__(256) void k_smoother(const float* __restrict__ fused,
        const float* __restrict__ w1g, const float* __restrict__ b1g,
        const float* __restrict__ W2Tg, const float* __restrict__ b2g,
        const float* __restrict__ w3g, const float* __restrict__ b3g,
        float* __restrict__ sm, const int* __restrict__ mi,
        const int* __restrict__ jmax, float* __restrict__ finNext) {
#pragma clang fp contract(off)
    __shared__ float F[3][28];
    __shared__ float H1[32][25];   // 24 used + 1 pad
    __shared__ float H2[32][21];   // 20 used + 1 pad
    __shared__ float W2[5120];
    __shared__ float B2[32];
    int tid = threadIdx.x;
    int BASE = blockIdx.x * SROWS;

    for (int li = tid; li < 84; li += 256) {
        int c = li / 28, i = li % 28;
        int t = BASE - 6 + i;
        F[c][i] = (t >= 0 && t < NPTS) ? fused[c * NPTS + t] : 0.0f;
    }
    for (int li = tid; li < 1280; li += 256)
        ((float4*)W2)[li] = ((const float4*)W2Tg)[li];
    if (tid < 32) B2[tid] = b2g[tid];
    __syncthreads();

    {
        int co = tid >> 3, pg = tid & 7;
        float wr[15];
#pragma unroll
        for (int q = 0; q < 15; ++q) wr[q] = w1g[co * 15 + q];
        float bias = b1g[co];
#pragma unroll
        for (int s = 0; s < 3; ++s) {
            int i = pg * 3 + s;
            int t = BASE - 4 + i;
            float acc = 0.0f;
#pragma unroll
            for (int k = 0; k < 5; ++k)
#pragma unroll
                for (int ci = 0; ci < 3; ++ci)
                    acc = __builtin_fmaf(F[ci][i + k], wr[ci * 5 + k], acc);
            H1[co][i] = (t >= 0 && t < NPTS) ? fmaxf(acc + bias, 0.0f) : 0.0f;
        }
    }
    __syncthreads();

    {
        int cq = tid & 7, pq = tid >> 3;
        if (pq < 10) {
            int i2 = pq * 2;
            int co0 = cq * 4;
            float acc00 = 0.f, acc01 = 0.f, acc02 = 0.f, acc03 = 0.f;
            float acc10 = 0.f, acc11 = 0.f, acc12 = 0.f, acc13 = 0.f;
            for (int k = 0; k < 5; ++k) {
#pragma unroll
                for (int ci = 0; ci < 32; ++ci) {
                    float in0 = H1[ci][i2 + k];
                    float in1 = H1[ci][i2 + k + 1];
                    const float4 wv = *(const float4*)&W2[(ci * 5 + k) * 32 + co0];
                    acc00 = __builtin_fmaf(in0, wv.x, acc00);
                    acc01 = __builtin_fmaf(in0, wv.y, acc01);
                    acc02 = __builtin_fmaf(in0, wv.z, acc02);
                    acc03 = __builtin_fmaf(in0, wv.w, acc03);
                    acc10 = __builtin_fmaf(in1, wv.x, acc10);
                    acc11 = __builtin_fmaf(in1, wv.y, acc11);
                    acc12 = __builtin_fmaf(in1, wv.z, acc12);
                    acc13 = __builtin_fmaf(in1, wv.w, acc13);
                }
            }
            int t0 = BASE - 2 + i2, t1 = t0 + 1;
            bool ok0 = (t0 >= 0 && t0 < NPTS), ok1 = (t1 >= 0 && t1 < NPTS);
            H2[co0 + 0][i2]     = ok0 ? fmaxf(acc00 + B2[co0 + 0], 0.0f) : 0.0f;
            H2[co0 + 1][i2]     = ok0 ? fmaxf(acc01 + B2[co0 + 1], 0.0f) : 0.0f;
            H2[co0 + 2][i2]     = ok0 ? fmaxf(acc02 + B2[co0 + 2], 0.0f) : 0.0f;
            H2[co0 + 3][i2]     = ok0 ? fmaxf(acc03 + B2[co0 + 3], 0.0f) : 0.0f;
            H2[co0 + 0][i2 + 1] = ok1 ? fmaxf(acc10 + B2[co0 + 0], 0.0f) : 0.0f;
            H2[co0 + 1][i2 + 1] = ok1 ? fmaxf(acc11 + B2[co0 + 1], 0.0f) : 0.0f;
            H2[co0 + 2][i2 + 1] = ok1 ? fmaxf(acc12 + B2[co0 + 2], 0.0f) : 0.0f;
            H2[co0 + 3][i2 + 1] = ok1 ? fmaxf(acc13 + B2[co0 + 3], 0.0f) : 0.0f;
        }
    }
    __syncthreads();

    if (tid < 48) {
        int co = tid >> 4, p = tid & 15;
        float wr[160];
        const float4* w3v = (const float4*)(w3g + co * 160);
#pragma unroll
        for (int q = 0; q < 40; ++q) {
            float4 v = w3v[q];
            wr[q * 4 + 0] = v.x; wr[q * 4 + 1] = v.y;
            wr[q * 4 + 2] = v.z; wr[q * 4 + 3] = v.w;
        }
        float acc = 0.0f;
#pragma unroll
        for (int k = 0; k < 5; ++k)
#pragma unroll
            for (int ci = 0; ci < 32; ++ci)
                acc = __builtin_fmaf(H2[ci][p + k], wr[ci * 5 + k], acc);
        float val = acc + b3g[co];
        int jj = BASE + p;
        sm[jj * 3 + co] = val;
        int kk = mi[jj];
        if (jmax[kk] == jj) finNext[kk * 3 + co] = val;
    }
}

// ---------------------------------------------------------------------------
__global__ void k_merge(const float* __restrict__ fin, float* __restrict__ out) {
#pragma clang fp contract(off)
    int pos = blockIdx.x * 256 + threadIdx.x;
    if (pos >= TOTAL) return;
    int imax = pos / STRIDE; if (imax > NCH - 1) imax = NCH - 1;
    int imin = (pos >= NPTS) ? ((pos - NPTS) / STRIDE + 1) : 0;
    float a0 = 0.0f, a1 = 0.0f, a2 = 0.0f, wsum = 0.0f;
    const float kstep = 0.9f / 1227.0f;
    for (int i = imin; i <= imax; ++i) {
        int t = pos - i * STRIDE;
        float cw;
        if (t < FADE)                cw = 0.1f + (float)t * kstep;
        else if (t >= NPTS - FADE)   cw = 1.0f - (float)(t - (NPTS - FADE)) * kstep;
        else                         cw = 1.0f;
        const float* v = fin + (i * NPTS + t) * 3;
        a0 += cw * v[0];
        a1 += cw * v[1];
        a2 += cw * v[2];
        wsum += cw;
    }
    float wm = fmaxf(wsum, 1e-8f);
    out[pos * 3 + 0] = a0 / wm;
    out[pos * 3 + 1] = a1 / wm;
    out[pos * 3 + 2] = a2 / wm;
}

// ---------------------------------------------------------------------------
extern "C" void kernel_launch(void* const* d_in, const int* in_sizes, int n_in,
                              void* d_out, int out_size, void* d_ws, size_t ws_size,
                              hipStream_t stream) {
    const float* chunks = (const float*)d_in[0];
    const float* bs_w1 = (const float*)d_in[1];
    const float* bs_b1 = (const float*)d_in[2];
    const float* bs_w2 = (const float*)d_in[3];
    const float* bs_b2 = (const float*)d_in[4];
    const float* bs_w3 = (const float*)d_in[5];
    const float* bs_b3 = (const float*)d_in[6];
    const float* wp_w1 = (const float*)d_in[7];
    const float* wp_b1 = (const float*)d_in[8];
    const float* wp_w2 = (const float*)d_in[9];
    const float* wp_b2 = (const float*)d_in[10];
    const float* wp_w3 = (const float*)d_in[11];
    const float* wp_b3 = (const float*)d_in[12];

    float4* C4all   = (float4*)d_ws;                          // 7*8192 float4 (16B-aligned base)
    float* fin      = (float*)(C4all + (NCH - 1) * NPTS);     // 196608 f32
    float* fused    = fin + NCH * NPTS * 3;                   // 24576 f32
    int*   mi       = (int*)(fused + 3 * NPTS);               // 8192 i32
    int*   jmax_all = mi + NPTS;                              // 57344 i32
    float* W2T      = (float*)(jmax_all + (NCH - 1) * NPTS);  // 5120 f32
    // total ~2.1 MB

    k_setup<<<768, 256, 0, stream>>>(chunks, fin, jmax_all, C4all, bs_w2, W2T);

    for (int i = 1; i < NCH; ++i) {
        float* P  = fin + (i - 1) * NPTS * 3;
        float* Pn = fin + i * NPTS * 3;
        const float4* C4 = C4all + (size_t)(i - 1) * NPTS;
        int* jmax = jmax_all + (i - 1) * NPTS;

        k_nn<<<NPTS / QW, 1024, 0, stream>>>(P, C4, wp_w1, wp_b1, wp_w2, wp_b2,
                                             wp_w3, wp_b3, fused, mi, jmax);
        k_smoother<<<NPTS / SROWS, 256, 0, stream>>>(fused, bs_w1, bs_b1, W2T, bs_b2,
                                                     bs_w3, bs_b3, P, mi, jmax, Pn);
    }

    k_merge<<<200, 256, 0, stream>>>(fin, (float*)d_out);
}